// Round 1
// baseline (781.624 us; speedup 1.0000x reference)
//
#include <hip/hip_runtime.h>

// Problem: AttentionBlock — x(8,1024,4,256) fp32, full 4096x4096 attention per
// batch (heads merged), qkv interleaved (e = 3*dd + which), then MLP 256->1024->256.
// Strategy: bf16 MFMA 16x16x32 everywhere (threshold 0.129 allows it).
// ws layout (needs 66 MB):
//   0        : w_qkv bf16 (768x256)
//   512K     : w1 bf16 (1024x256)
//   1M       : w2 bf16 (256x1024)
//   2M..18M  : XN bf16 (32768x256)   [LN1 out, later LN2 out]
//   18M..34M : Q bf16 [b][i][d]
//   34M..50M : K bf16 [b][i][d]
//   50M..66M : V^T bf16 [b][d][i]

typedef __attribute__((ext_vector_type(8))) short bf16x8;
typedef __attribute__((ext_vector_type(4))) float f32x4;

static __device__ __forceinline__ short f2bf(float f) {
    union { float f; unsigned u; } v; v.f = f;
    unsigned r = (v.u + 0x7FFFu + ((v.u >> 16) & 1u)) >> 16;
    return (short)r;
}

// ---------------- weights fp32 -> bf16 ----------------
__global__ __launch_bounds__(256) void k_cvt(const float* __restrict__ wqkv,
                                             const float* __restrict__ w1,
                                             const float* __restrict__ w2,
                                             short* __restrict__ owqkv,
                                             short* __restrict__ ow1,
                                             short* __restrict__ ow2) {
    int i = blockIdx.x * 256 + threadIdx.x;          // grid covers 262144
    if (i < 196608) owqkv[i] = f2bf(wqkv[i]);
    if (i < 262144) { ow1[i] = f2bf(w1[i]); ow2[i] = f2bf(w2[i]); }
}

// ---------------- layernorm: one wave per row of 256 ----------------
__global__ __launch_bounds__(256) void k_ln(const float* __restrict__ x,
                                            const float* __restrict__ g,
                                            const float* __restrict__ bta,
                                            short* __restrict__ out) {
    int w = threadIdx.x >> 6, lane = threadIdx.x & 63;
    long row = (long)blockIdx.x * 4 + w;
    float4 v = *((const float4*)(x + row * 256) + lane);
    float s = v.x + v.y + v.z + v.w;
    float q = v.x * v.x + v.y * v.y + v.z * v.z + v.w * v.w;
    for (int off = 1; off < 64; off <<= 1) {
        s += __shfl_xor(s, off);
        q += __shfl_xor(q, off);
    }
    float mean = s * (1.0f / 256.0f);
    float var = q * (1.0f / 256.0f) - mean * mean;
    float rstd = rsqrtf(var + 1e-5f);
    float4 gg = *((const float4*)g + lane);
    float4 bb = *((const float4*)bta + lane);
    short4 o;
    o.x = f2bf((v.x - mean) * rstd * gg.x + bb.x);
    o.y = f2bf((v.y - mean) * rstd * gg.y + bb.y);
    o.z = f2bf((v.z - mean) * rstd * gg.z + bb.z);
    o.w = f2bf((v.w - mean) * rstd * gg.w + bb.w);
    *((short4*)(out + row * 256) + lane) = o;
}

// ---------------- QKV projection GEMM + de-interleave scatter ----------------
// C[32768, 768] = XN[32768,256] * Wqkv[768,256]^T  (NT). 64x64 tile per block.
__global__ __launch_bounds__(256) void k_qkv(const short* __restrict__ xn,
                                             const short* __restrict__ wb,
                                             short* __restrict__ Q,
                                             short* __restrict__ K,
                                             short* __restrict__ VT) {
    __shared__ __attribute__((aligned(16))) short lds_a[64 * 264];
    __shared__ __attribute__((aligned(16))) short lds_b[64 * 264];
    int t = threadIdx.x;
    int m0 = blockIdx.y * 64, n0 = blockIdx.x * 64;
    const int4* ga = (const int4*)xn;   // 32 int4 per row
    const int4* gb = (const int4*)wb;
    int4* la = (int4*)lds_a;
    int4* lb = (int4*)lds_b;
    for (int it = 0; it < 8; it++) {
        int c = t + 256 * it;           // 2048 chunks: 64 rows x 32
        int r = c >> 5, k = c & 31;
        la[r * 33 + k] = ga[(long)(m0 + r) * 32 + k];
        lb[r * 33 + k] = gb[(n0 + r) * 32 + k];
    }
    __syncthreads();
    int w = t >> 6, lane = t & 63, ln = lane & 15, qd = lane >> 4;
    int moff = (w >> 1) * 32, noff = (w & 1) * 32;
    f32x4 acc[2][2] = {};
    for (int ks = 0; ks < 8; ks++) {
        bf16x8 a0 = *(const bf16x8*)&lds_a[(moff + ln) * 264 + ks * 32 + qd * 8];
        bf16x8 a1 = *(const bf16x8*)&lds_a[(moff + 16 + ln) * 264 + ks * 32 + qd * 8];
        bf16x8 b0 = *(const bf16x8*)&lds_b[(noff + ln) * 264 + ks * 32 + qd * 8];
        bf16x8 b1 = *(const bf16x8*)&lds_b[(noff + 16 + ln) * 264 + ks * 32 + qd * 8];
        acc[0][0] = __builtin_amdgcn_mfma_f32_16x16x32_bf16(a0, b0, acc[0][0], 0, 0, 0);
        acc[0][1] = __builtin_amdgcn_mfma_f32_16x16x32_bf16(a0, b1, acc[0][1], 0, 0, 0);
        acc[1][0] = __builtin_amdgcn_mfma_f32_16x16x32_bf16(a1, b0, acc[1][0], 0, 0, 0);
        acc[1][1] = __builtin_amdgcn_mfma_f32_16x16x32_bf16(a1, b1, acc[1][1], 0, 0, 0);
    }
    for (int mi = 0; mi < 2; mi++)
        for (int nj = 0; nj < 2; nj++)
            for (int rg = 0; rg < 4; rg++) {
                float v = acc[mi][nj][rg];
                int gr = m0 + moff + mi * 16 + qd * 4 + rg;   // global row (b*4096+i)
                int e = n0 + noff + nj * 16 + ln;             // 0..767
                int which = e % 3, dd = e / 3;
                short bv = f2bf(v);
                if (which == 0) Q[(long)gr * 256 + dd] = bv;
                else if (which == 1) K[(long)gr * 256 + dd] = bv;
                else {
                    int b = gr >> 12, i = gr & 4095;
                    VT[((long)b * 256 + dd) * 4096 + i] = bv;
                }
            }
}

// ---------------- flash attention: x2 = x + softmax(QK^T/16) V ----------------
// block = 256 thr (4 waves x 16 q-rows = BM 64). BN = 32 keys/iter.
__global__ __launch_bounds__(256) void k_attn(const short* __restrict__ Q,
                                              const short* __restrict__ K,
                                              const short* __restrict__ VT,
                                              const float* __restrict__ x,
                                              float* __restrict__ out) {
    __shared__ __attribute__((aligned(16))) short lds_k[32 * 264];
    __shared__ __attribute__((aligned(16))) short lds_v[256 * 40];
    __shared__ __attribute__((aligned(16))) short lds_p[4 * 16 * 40];
    int t = threadIdx.x;
    int b = blockIdx.y;
    int m0 = blockIdx.x * 64;
    int w = t >> 6, lane = t & 63, ln = lane & 15, qd = lane >> 4;

    bf16x8 qf[8];
    {
        const bf16x8* gq = (const bf16x8*)(Q + ((long)(b * 4096 + m0 + w * 16 + ln)) * 256);
        for (int ks = 0; ks < 8; ks++) qf[ks] = gq[ks * 4 + qd];
    }
    f32x4 O[16] = {};
    float m_r[4] = {-1e30f, -1e30f, -1e30f, -1e30f};
    float l_r[4] = {0.f, 0.f, 0.f, 0.f};
    const int4* gk = (const int4*)K + (long)b * 4096 * 32;
    const int4* gv = (const int4*)VT + (long)b * 256 * 512;
    int4* lk = (int4*)lds_k;
    int4* lv = (int4*)lds_v;
    const float sc = 0.0625f * 1.44269504f;   // 1/sqrt(256) * log2(e)

    for (int j0 = 0; j0 < 4096; j0 += 32) {
        for (int it = 0; it < 4; it++) {
            int c = t + 256 * it;             // 1024 chunks each
            lk[(c >> 5) * 33 + (c & 31)] = gk[(j0 + (c >> 5)) * 32 + (c & 31)];
            lv[(c >> 2) * 5 + (c & 3)] = gv[(c >> 2) * 512 + (j0 >> 3) + (c & 3)];
        }
        __syncthreads();
        f32x4 s0 = {}, s1 = {};
        for (int ks = 0; ks < 8; ks++) {
            bf16x8 k0 = *(const bf16x8*)&lds_k[ln * 264 + ks * 32 + qd * 8];
            bf16x8 k1 = *(const bf16x8*)&lds_k[(16 + ln) * 264 + ks * 32 + qd * 8];
            s0 = __builtin_amdgcn_mfma_f32_16x16x32_bf16(qf[ks], k0, s0, 0, 0, 0);
            s1 = __builtin_amdgcn_mfma_f32_16x16x32_bf16(qf[ks], k1, s1, 0, 0, 0);
        }
        float alpha[4];
        for (int rg = 0; rg < 4; rg++) {
            float v0 = s0[rg] * sc, v1 = s1[rg] * sc;
            float mx = fmaxf(v0, v1);
            mx = fmaxf(mx, __shfl_xor(mx, 1));
            mx = fmaxf(mx, __shfl_xor(mx, 2));
            mx = fmaxf(mx, __shfl_xor(mx, 4));
            mx = fmaxf(mx, __shfl_xor(mx, 8));
            float mn = fmaxf(m_r[rg], mx);
            alpha[rg] = exp2f(m_r[rg] - mn);
            m_r[rg] = mn;
            float p0 = exp2f(v0 - mn), p1 = exp2f(v1 - mn);
            float ps = p0 + p1;
            ps += __shfl_xor(ps, 1);
            ps += __shfl_xor(ps, 2);
            ps += __shfl_xor(ps, 4);
            ps += __shfl_xor(ps, 8);
            l_r[rg] = l_r[rg] * alpha[rg] + ps;
            int prow = w * 16 + qd * 4 + rg;
            lds_p[prow * 40 + ln] = f2bf(p0);
            lds_p[prow * 40 + 16 + ln] = f2bf(p1);
        }
        for (int dt = 0; dt < 16; dt++) {
            O[dt][0] *= alpha[0]; O[dt][1] *= alpha[1];
            O[dt][2] *= alpha[2]; O[dt][3] *= alpha[3];
        }
        asm volatile("s_waitcnt lgkmcnt(0)" ::: "memory");
        bf16x8 pa = *(const bf16x8*)&lds_p[(w * 16 + ln) * 40 + qd * 8];
        for (int dt = 0; dt < 16; dt++) {
            bf16x8 bv = *(const bf16x8*)&lds_v[(dt * 16 + ln) * 40 + qd * 8];
            O[dt] = __builtin_amdgcn_mfma_f32_16x16x32_bf16(pa, bv, O[dt], 0, 0, 0);
        }
        __syncthreads();
    }
    for (int dt = 0; dt < 16; dt++)
        for (int rg = 0; rg < 4; rg++) {
            int gr = m0 + w * 16 + qd * 4 + rg;
            int dd = dt * 16 + ln;
            long idx = ((long)(b * 4096 + gr)) * 256 + dd;
            out[idx] = x[idx] + O[dt][rg] / l_r[rg];
        }
}

// ---------------- fused MLP: out = x2 + silu(xn2 W1^T + b1) W2^T + b2 --------
// 64 rows/block, wave-private 16-row slabs, no __syncthreads.
__global__ __launch_bounds__(256) void k_mlp(const short* __restrict__ xn,
                                             const short* __restrict__ w1b,
                                             const short* __restrict__ w2b,
                                             const float* __restrict__ b1,
                                             const float* __restrict__ b2,
                                             float* __restrict__ out) {
    __shared__ __attribute__((aligned(16))) short lds_x[4 * 16 * 264];
    __shared__ __attribute__((aligned(16))) short lds_h[4 * 16 * 264];
    int t = threadIdx.x, w = t >> 6, lane = t & 63, ln = lane & 15, qd = lane >> 4;
    int R0 = blockIdx.x * 64 + w * 16;
    short* lxs = lds_x + w * 16 * 264;
    short* lhs = lds_h + w * 16 * 264;
    {
        int4* lx = (int4*)lxs;
        const int4* gx = (const int4*)xn;
        for (int it = 0; it < 8; it++) {
            int c = lane + 64 * it;       // 512 chunks: 16 rows x 32
            lx[(c >> 5) * 33 + (c & 31)] = gx[(long)(R0 + (c >> 5)) * 32 + (c & 31)];
        }
    }
    asm volatile("s_waitcnt lgkmcnt(0)" ::: "memory");
    bf16x8 a1f[8];
    for (int ks = 0; ks < 8; ks++)
        a1f[ks] = *(const bf16x8*)&lxs[ln * 264 + ks * 32 + qd * 8];
    f32x4 Oc[16] = {};
    const bf16x8* g1 = (const bf16x8*)w1b;   // row = 32 chunks
    const bf16x8* g2 = (const bf16x8*)w2b;   // row = 128 chunks
    for (int pass = 0; pass < 4; pass++) {
        for (int nt = 0; nt < 16; nt++) {
            int n0 = pass * 256 + nt * 16;
            f32x4 acc = {};
            for (int ks = 0; ks < 8; ks++) {
                bf16x8 bf = g1[(n0 + ln) * 32 + ks * 4 + qd];
                acc = __builtin_amdgcn_mfma_f32_16x16x32_bf16(a1f[ks], bf, acc, 0, 0, 0);
            }
            float bb = b1[n0 + ln];
            for (int rg = 0; rg < 4; rg++) {
                float z = acc[rg] + bb;
                float sv = z / (1.0f + __expf(-z));
                lhs[(qd * 4 + rg) * 264 + nt * 16 + ln] = f2bf(sv);
            }
        }
        asm volatile("s_waitcnt lgkmcnt(0)" ::: "memory");
        bf16x8 a2f[8];
        for (int ks = 0; ks < 8; ks++)
            a2f[ks] = *(const bf16x8*)&lhs[ln * 264 + ks * 32 + qd * 8];
        for (int nt = 0; nt < 16; nt++)
            for (int ks = 0; ks < 8; ks++) {
                bf16x8 bf = g2[(nt * 16 + ln) * 128 + pass * 32 + ks * 4 + qd];
                Oc[nt] = __builtin_amdgcn_mfma_f32_16x16x32_bf16(a2f[ks], bf, Oc[nt], 0, 0, 0);
            }
        asm volatile("s_waitcnt lgkmcnt(0)" ::: "memory");  // a2f reads done before next pass rewrites lhs
    }
    for (int nt = 0; nt < 16; nt++) {
        int dd = nt * 16 + ln;
        float bb = b2[dd];
        for (int rg = 0; rg < 4; rg++) {
            long idx = (long)(R0 + qd * 4 + rg) * 256 + dd;
            out[idx] = out[idx] + Oc[nt][rg] + bb;
        }
    }
}

extern "C" void kernel_launch(void* const* d_in, const int* in_sizes, int n_in,
                              void* d_out, int out_size, void* d_ws, size_t ws_size,
                              hipStream_t stream) {
    const float* x    = (const float*)d_in[0];
    const float* wqkv = (const float*)d_in[1];
    const float* g1   = (const float*)d_in[2];
    const float* be1  = (const float*)d_in[3];
    const float* g2   = (const float*)d_in[4];
    const float* be2  = (const float*)d_in[5];
    const float* w1   = (const float*)d_in[6];
    const float* b1   = (const float*)d_in[7];
    const float* w2   = (const float*)d_in[8];
    const float* b2   = (const float*)d_in[9];
    float* out = (float*)d_out;
    char* ws = (char*)d_ws;
    short* WQKV = (short*)(ws);
    short* W1B  = (short*)(ws + (512l << 10));
    short* W2B  = (short*)(ws + (1l << 20));
    short* XN   = (short*)(ws + (2l << 20));
    short* Qb   = (short*)(ws + (18l << 20));
    short* Kb   = (short*)(ws + (34l << 20));
    short* VTb  = (short*)(ws + (50l << 20));

    k_cvt<<<1024, 256, 0, stream>>>(wqkv, w1, w2, WQKV, W1B, W2B);
    k_ln<<<8192, 256, 0, stream>>>(x, g1, be1, XN);
    k_qkv<<<dim3(12, 512), 256, 0, stream>>>(XN, WQKV, Qb, Kb, VTb);
    k_attn<<<dim3(64, 8), 256, 0, stream>>>(Qb, Kb, VTb, x, out);
    k_ln<<<8192, 256, 0, stream>>>(out, g2, be2, XN);
    k_mlp<<<512, 256, 0, stream>>>(XN, W1B, W2B, b1, b2, out);
}